// Round 2
// baseline (960.237 us; speedup 1.0000x reference)
//
#include <hip/hip_runtime.h>
#include <hip/hip_bf16.h>
#include <math.h>

#define B_  2
#define S_  2048
#define H_  2048
#define NH_ 16
#define HD_ 128
#define M_  (B_*S_)   // 4096

typedef __bf16 bf16_t;
typedef _Float16 f16_t;
typedef __bf16 bf16x8 __attribute__((ext_vector_type(8)));
typedef __bf16 bf16x4 __attribute__((ext_vector_type(4)));
typedef _Float16 f16x4 __attribute__((ext_vector_type(4)));
typedef float  f32x4  __attribute__((ext_vector_type(4)));

__device__ __forceinline__ f32x4 mfma_bf16_32(bf16x8 a, bf16x8 b, f32x4 c) {
  return __builtin_amdgcn_mfma_f32_16x16x32_bf16(a, b, c, 0, 0, 0);
}
__device__ __forceinline__ f32x4 mfma_f16_16(f16x4 a, f16x4 b, f32x4 c) {
  return __builtin_amdgcn_mfma_f32_16x16x16f16(a, b, c, 0, 0, 0);
}
// async global->LDS, 16B per lane; lptr must be wave-uniform (lane i lands at lptr + i*16)
__device__ __forceinline__ void gl_lds16(const void* g, void* l) {
  __builtin_amdgcn_global_load_lds((const __attribute__((address_space(1))) void*)g,
                                   (__attribute__((address_space(3))) void*)l, 16, 0, 0);
}

// ---------------- fp32 -> bf16 convert ----------------
__global__ void cvt_f32_bf16(const float* __restrict__ src, bf16_t* __restrict__ dst, int n) {
  int stride = gridDim.x * blockDim.x * 4;
  for (int i = (blockIdx.x * blockDim.x + threadIdx.x) * 4; i < n; i += stride) {
    float4 v = *(const float4*)(src + i);
    bf16x4 o;
    o[0] = (bf16_t)v.x; o[1] = (bf16_t)v.y; o[2] = (bf16_t)v.z; o[3] = (bf16_t)v.w;
    *(bf16x4*)(dst + i) = o;
  }
}

// ---------------- bf16 MFMA GEMM, m97-style global_load_lds staging ----------------
// C[m,n] = sum_k A[m,k] * Bt[n,k]
// MODE 0: fused QKV epilogue (N=6144): n<2048 -> Q scatter [B,NH,S,HD] bf16,
//         n<4096 -> K scatter, else -> V transpose [B,NH,HD,S] fp16
// MODE 1: fp32 row-major [M, H_]
template<int MODE>
__global__ __launch_bounds__(256, 3)
void gemm_mfma(const bf16_t* __restrict__ A, const bf16_t* __restrict__ Bt,
               bf16_t* __restrict__ outQ, bf16_t* __restrict__ outK,
               f16_t* __restrict__ outV, float* __restrict__ outF, int K) {
  __shared__ bf16_t sA[128 * 64];   // 16 KB, unpadded (global_load_lds needs linear layout)
  __shared__ bf16_t sB[128 * 64];
  const int tid  = threadIdx.x;
  const int lane = tid & 63;
  const int w    = tid >> 6;
  const int col  = lane & 15;
  const int quad = lane >> 4;
  const int w_m  = (w & 1) * 64;
  const int w_n  = (w >> 1) * 64;
  const int m_blk = blockIdx.y * 128;
  const int n_blk = blockIdx.x * 128;

  const int arow = lane >> 3;        // row within 8-row segment
  const int acol = (lane & 7) * 8;   // element col (16B chunks)

  const bf16_t* Abase = A  + (size_t)m_blk * K;
  const bf16_t* Bbase = Bt + (size_t)n_blk * K;

  f32x4 acc[4][4] = {};

  for (int kk = 0; kk < K; kk += 64) {
    __syncthreads();   // previous-iteration readers done
#pragma unroll
    for (int p = 0; p < 4; ++p) {
      int seg = w * 4 + p;                 // 16 segments of 8 rows x 64 cols
      int row = seg * 8 + arow;
      gl_lds16(Abase + (size_t)row * K + kk + acol, &sA[seg * 512]);
      gl_lds16(Bbase + (size_t)row * K + kk + acol, &sB[seg * 512]);
    }
    __syncthreads();   // drains vmcnt: LDS tiles visible
#pragma unroll
    for (int kc = 0; kc < 2; ++kc) {
      bf16x8 af[4], bfr[4];
#pragma unroll
      for (int i = 0; i < 4; ++i) {
        af[i]  = *(const bf16x8*)&sA[(w_m + i * 16 + col) * 64 + kc * 32 + quad * 8];
        bfr[i] = *(const bf16x8*)&sB[(w_n + i * 16 + col) * 64 + kc * 32 + quad * 8];
      }
#pragma unroll
      for (int mi = 0; mi < 4; ++mi)
#pragma unroll
        for (int ni = 0; ni < 4; ++ni)
          acc[mi][ni] = mfma_bf16_32(af[mi], bfr[ni], acc[mi][ni]);
    }
  }

  const int sel = n_blk >> 11;   // block-uniform (ranges are 2048-aligned)
#pragma unroll
  for (int mi = 0; mi < 4; ++mi)
#pragma unroll
    for (int ni = 0; ni < 4; ++ni)
#pragma unroll
      for (int r = 0; r < 4; ++r) {
        int m = m_blk + w_m + mi * 16 + quad * 4 + r;
        int n = n_blk + w_n + ni * 16 + col;
        float v = acc[mi][ni][r];
        if (MODE == 0) {
          int n_l = n & (H_ - 1);
          int head = n_l >> 7, hd = n_l & (HD_ - 1);
          int b = m >> 11, s = m & (S_ - 1);
          if (sel == 2) {
            outV[(((size_t)(b * NH_ + head)) * HD_ + hd) * S_ + s] = (f16_t)v;
          } else {
            size_t idx = (((size_t)(b * NH_ + head)) * S_ + s) * HD_ + hd;
            if (sel == 0) outQ[idx] = (bf16_t)v;
            else          outK[idx] = (bf16_t)v;
          }
        } else {
          outF[(size_t)m * H_ + n] = v;
        }
      }
}

// ---------------- RoPE (in-place on [B,NH,S,HD] bf16) ----------------
__global__ void rope_kernel(bf16_t* __restrict__ X) {
  int i = blockIdx.x * blockDim.x + threadIdx.x;  // B*NH*S*64 threads
  int d  = i & 63;
  int s  = (i >> 6) & (S_ - 1);
  int bh = i >> 17;
  if (bh >= B_ * NH_) return;
  float ang = (float)s * powf(10000.0f, -(float)d * (1.0f / 64.0f));
  float c = cosf(ang), sn = sinf(ang);
  size_t base = ((size_t)bh * S_ + s) * HD_ + d;
  float x1 = (float)X[base], x2 = (float)X[base + 64];
  X[base]      = (bf16_t)(x1 * c - x2 * sn);
  X[base + 64] = (bf16_t)(x2 * c + x1 * sn);
}

// ---------------- Flash causal attention (S^T form) ----------------
// St = K.Q^T : C-layout col = q (lane&15), row = k (quad*4+r)
//   -> softmax over k is in-register (16 vals) + shfl_xor(16),(32)
//   -> post-exp P^T fragment IS the B-operand of mfma_f32_16x16x16f16
// O^T = V^T.P^T accumulated in C-layout (col=q, row=d)
// Q,K: [B,NH,S,HD] bf16; Vt: [B,NH,HD,S] fp16; Out: [B,S,H] bf16
__global__ __launch_bounds__(256, 4)
void flash_attn(const bf16_t* __restrict__ Q, const bf16_t* __restrict__ K,
                const f16_t* __restrict__ Vt, bf16_t* __restrict__ Out) {
  __shared__ bf16_t sK[64 * 128];  // 16 KB, linear for global_load_lds
  __shared__ f16_t  sV[128 * 64];  // 16 KB [d][s_tile]

  const int tid  = threadIdx.x;
  const int lane = tid & 63;
  const int w    = tid >> 6;
  const int col  = lane & 15;
  const int quad = lane >> 4;

  const int qt = gridDim.x - 1 - blockIdx.x;  // long blocks first (tail balance)
  const int bh = blockIdx.y;
  const int b  = bh >> 4;
  const int h  = bh & (NH_ - 1);

  const bf16_t* Qb = Q  + (size_t)bh * S_ * HD_;
  const bf16_t* Kb = K  + (size_t)bh * S_ * HD_;
  const f16_t*  Vb = Vt + (size_t)bh * HD_ * S_;

  // Q fragments in registers (wave owns 16 q-rows), pre-scaled by 1/sqrt(HD)
  const float scale = 0.08838834764831845f;
  const bf16_t* Qrow = Qb + (size_t)(qt * 64 + w * 16 + col) * HD_;
  bf16x8 qf[4];
#pragma unroll
  for (int kc = 0; kc < 4; ++kc) {
    qf[kc] = *(const bf16x8*)(Qrow + kc * 32 + quad * 8);
#pragma unroll
    for (int j = 0; j < 8; ++j) qf[kc][j] = (bf16_t)((float)qf[kc][j] * scale);
  }

  f32x4 oacc[8] = {};
  float m_i = -1e30f, l_i = 0.f;

  for (int kt = 0; kt <= qt; ++kt) {
    __syncthreads();
    // stage K tile (64x128 bf16) and V tile (128x64 f16) via async copy
#pragma unroll
    for (int p = 0; p < 4; ++p) {
      int seg = w * 4 + p;
      int krow = seg * 4 + (lane >> 4);
      gl_lds16(Kb + (size_t)(kt * 64 + krow) * HD_ + (lane & 15) * 8, &sK[seg * 512]);
      int vrow = seg * 8 + (lane >> 3);
      gl_lds16(Vb + (size_t)vrow * S_ + kt * 64 + (lane & 7) * 8, &sV[seg * 512]);
    }
    __syncthreads();

    // St = K.Q^T  (4 k-tiles of 16)
    f32x4 st[4] = {};
#pragma unroll
    for (int kc = 0; kc < 4; ++kc) {
#pragma unroll
      for (int t = 0; t < 4; ++t) {
        bf16x8 kf = *(const bf16x8*)&sK[(t * 16 + col) * 128 + kc * 32 + quad * 8];
        st[t] = mfma_bf16_32(kf, qf[kc], st[t]);
      }
    }

    // causal mask (only the diagonal tile, which is the last iteration)
    if (kt == qt) {
      int ql = w * 16 + col;
#pragma unroll
      for (int t = 0; t < 4; ++t)
#pragma unroll
        for (int r = 0; r < 4; ++r)
          if (t * 16 + quad * 4 + r > ql) st[t][r] = -1e30f;
    }

    // online softmax: per-lane q, k spread over regs (16) + quads
    float mx = st[0][0];
#pragma unroll
    for (int t = 0; t < 4; ++t)
#pragma unroll
      for (int r = 0; r < 4; ++r) mx = fmaxf(mx, st[t][r]);
    mx = fmaxf(mx, __shfl_xor(mx, 16, 64));
    mx = fmaxf(mx, __shfl_xor(mx, 32, 64));
    float mn = fmaxf(m_i, mx);
    float alpha = __expf(m_i - mn);
    m_i = mn;

    float sum = 0.f;
    f16x4 pf[4];
#pragma unroll
    for (int t = 0; t < 4; ++t)
#pragma unroll
      for (int r = 0; r < 4; ++r) {
        float p = __expf(st[t][r] - mn);
        sum += p;
        pf[t][r] = (f16_t)p;
      }
    sum += __shfl_xor(sum, 16, 64);
    sum += __shfl_xor(sum, 32, 64);
    l_i = l_i * alpha + sum;

#pragma unroll
    for (int dt = 0; dt < 8; ++dt)
#pragma unroll
      for (int r = 0; r < 4; ++r) oacc[dt][r] *= alpha;

    // O^T += V^T.P^T  — P fragment straight from registers
#pragma unroll
    for (int t = 0; t < 4; ++t) {
      const int vcol = t * 16 + quad * 4;
#pragma unroll
      for (int dt = 0; dt < 8; ++dt) {
        f16x4 vf = *(const f16x4*)&sV[(dt * 16 + col) * 64 + vcol];
        oacc[dt] = mfma_f16_16(vf, pf[t], oacc[dt]);
      }
    }
  }

  float inv = 1.0f / l_i;
  int qg = qt * 64 + w * 16 + col;
  bf16_t* Orow = Out + ((size_t)b * S_ + qg) * H_ + h * HD_;
#pragma unroll
  for (int dt = 0; dt < 8; ++dt) {
    bf16x4 o4;
#pragma unroll
    for (int r = 0; r < 4; ++r) o4[r] = (bf16_t)(oacc[dt][r] * inv);
    *(bf16x4*)(Orow + dt * 16 + quad * 4) = o4;
  }
}

// ---------------- launch ----------------
extern "C" void kernel_launch(void* const* d_in, const int* in_sizes, int n_in,
                              void* d_out, int out_size, void* d_ws, size_t ws_size,
                              hipStream_t stream) {
  const float* hs = (const float*)d_in[0];
  // d_in[1] = attention_mask: exactly causal tril(0,-1e9) -> applied analytically
  const float* Wq = (const float*)d_in[2];
  const float* Wk = (const float*)d_in[3];
  const float* Wv = (const float*)d_in[4];
  const float* Wo = (const float*)d_in[5];
  float* out = (float*)d_out;

  char* ws = (char*)d_ws;
  size_t off = 0;
  auto alloc = [&](size_t bytes) -> void* {
    void* p = ws + off;
    off += (bytes + 255) & ~(size_t)255;
    return p;
  };
  bf16_t* hs_b  = (bf16_t*)alloc((size_t)M_ * H_ * 2);
  bf16_t* wqkv  = (bf16_t*)alloc((size_t)3 * H_ * H_ * 2);  // Wq|Wk|Wv contiguous
  bf16_t* wo_b  = (bf16_t*)alloc((size_t)H_ * H_ * 2);
  bf16_t* Qbuf  = (bf16_t*)alloc((size_t)M_ * H_ * 2);
  bf16_t* Kbuf  = (bf16_t*)alloc((size_t)M_ * H_ * 2);
  f16_t*  Vtbuf = (f16_t*)alloc((size_t)M_ * H_ * 2);
  bf16_t* attn  = (bf16_t*)alloc((size_t)M_ * H_ * 2);

  cvt_f32_bf16<<<4096, 256, 0, stream>>>(hs, hs_b, M_ * H_);
  cvt_f32_bf16<<<2048, 256, 0, stream>>>(Wq, wqkv,             H_ * H_);
  cvt_f32_bf16<<<2048, 256, 0, stream>>>(Wk, wqkv + H_ * H_,   H_ * H_);
  cvt_f32_bf16<<<2048, 256, 0, stream>>>(Wv, wqkv + 2 * H_ * H_, H_ * H_);
  cvt_f32_bf16<<<2048, 256, 0, stream>>>(Wo, wo_b, H_ * H_);

  // fused QKV projection: [4096 x 6144] = hs_b . wqkv^T
  gemm_mfma<0><<<dim3(48, 32), 256, 0, stream>>>(hs_b, wqkv, Qbuf, Kbuf, Vtbuf,
                                                 nullptr, H_);

  int rope_threads = B_ * NH_ * S_ * 64;
  rope_kernel<<<rope_threads / 256, 256, 0, stream>>>(Qbuf);
  rope_kernel<<<rope_threads / 256, 256, 0, stream>>>(Kbuf);

  flash_attn<<<dim3(32, 32), 256, 0, stream>>>(Qbuf, Kbuf, Vtbuf, attn);

  // output projection (fp32 out)
  gemm_mfma<1><<<dim3(16, 32), 256, 0, stream>>>(attn, wo_b, nullptr, nullptr,
                                                 nullptr, out, H_);
}

// Round 3
// 493.638 us; speedup vs baseline: 1.9452x; 1.9452x over previous
//
#include <hip/hip_runtime.h>
#include <hip/hip_bf16.h>
#include <math.h>

#define B_  2
#define S_  2048
#define H_  2048
#define NH_ 16
#define HD_ 128
#define M_  (B_*S_)   // 4096

typedef __bf16 bf16_t;
typedef _Float16 f16_t;
typedef __bf16 bf16x8 __attribute__((ext_vector_type(8)));
typedef __bf16 bf16x4 __attribute__((ext_vector_type(4)));
typedef _Float16 f16x4 __attribute__((ext_vector_type(4)));
typedef float  f32x4  __attribute__((ext_vector_type(4)));

__device__ __forceinline__ f32x4 mfma_bf16_32(bf16x8 a, bf16x8 b, f32x4 c) {
  return __builtin_amdgcn_mfma_f32_16x16x32_bf16(a, b, c, 0, 0, 0);
}
__device__ __forceinline__ f32x4 mfma_f16_16(f16x4 a, f16x4 b, f32x4 c) {
  return __builtin_amdgcn_mfma_f32_16x16x16f16(a, b, c, 0, 0, 0);
}
// async global->LDS, 16B per lane; LDS base wave-uniform (lane i -> base + i*16)
__device__ __forceinline__ void gl_lds16(const void* g, void* l) {
  __builtin_amdgcn_global_load_lds((const __attribute__((address_space(1))) void*)g,
                                   (__attribute__((address_space(3))) void*)l, 16, 0, 0);
}

// ---------------- fp32 -> bf16 convert ----------------
__global__ void cvt_f32_bf16(const float* __restrict__ src, bf16_t* __restrict__ dst, int n) {
  int stride = gridDim.x * blockDim.x * 4;
  for (int i = (blockIdx.x * blockDim.x + threadIdx.x) * 4; i < n; i += stride) {
    float4 v = *(const float4*)(src + i);
    bf16x4 o;
    o[0] = (bf16_t)v.x; o[1] = (bf16_t)v.y; o[2] = (bf16_t)v.z; o[3] = (bf16_t)v.w;
    *(bf16x4*)(dst + i) = o;
  }
}

// ---------------- bf16 MFMA GEMM, global_load_lds + XOR-swizzled LDS ----------------
// LDS tile: [row][chunk] of 16B chunks; LDS (row,c) holds GLOBAL chunk c^(row&7).
// Readers: global chunk g at row r lives at LDS chunk g^(r&7). Read rows have
// row&7 == col&7 -> 16 cols spread over all 8 bank groups (depth 8 = b128 floor).
// MODE 0: fused QKV epilogue (N=6144): n<2048 -> Q [B,NH,S,HD] bf16,
//         n<4096 -> K scatter, else -> V transpose [B,NH,HD,S] fp16
// MODE 1: fp32 row-major [M, H_]
template<int MODE>
__global__ __launch_bounds__(256, 3)
void gemm_mfma(const bf16_t* __restrict__ A, const bf16_t* __restrict__ Bt,
               bf16_t* __restrict__ outQ, bf16_t* __restrict__ outK,
               f16_t* __restrict__ outV, float* __restrict__ outF, int K) {
  __shared__ bf16_t sA[128 * 64];   // 16 KB
  __shared__ bf16_t sB[128 * 64];
  const int tid  = threadIdx.x;
  const int lane = tid & 63;
  const int w    = tid >> 6;
  const int col  = lane & 15;
  const int quad = lane >> 4;
  const int w_m  = (w & 1) * 64;
  const int w_n  = (w >> 1) * 64;
  const int m_blk = blockIdx.y * 128;
  const int n_blk = blockIdx.x * 128;

  const int srow   = lane >> 3;                    // row within 8-row segment
  const int schunk = (lane & 7) ^ (lane >> 3);     // swizzled source chunk (row&7 == lane>>3)

  const bf16_t* Abase = A  + (size_t)m_blk * K;
  const bf16_t* Bbase = Bt + (size_t)n_blk * K;

  f32x4 acc[4][4] = {};

  for (int kk = 0; kk < K; kk += 64) {
    __syncthreads();   // previous-iteration readers done
#pragma unroll
    for (int p = 0; p < 4; ++p) {
      int seg = w * 4 + p;                 // 16 segments of 8 rows x 8 chunks
      int row = seg * 8 + srow;
      gl_lds16(Abase + (size_t)row * K + kk + schunk * 8, &sA[seg * 512]);
      gl_lds16(Bbase + (size_t)row * K + kk + schunk * 8, &sB[seg * 512]);
    }
    __syncthreads();   // drains vmcnt: LDS tiles visible
#pragma unroll
    for (int kc = 0; kc < 2; ++kc) {
      bf16x8 af[4], bfr[4];
      const int cs = (kc * 4 + quad) ^ (col & 7);  // swizzled chunk for this fragment
#pragma unroll
      for (int i = 0; i < 4; ++i) {
        af[i]  = *(const bf16x8*)&sA[(w_m + i * 16 + col) * 64 + cs * 8];
        bfr[i] = *(const bf16x8*)&sB[(w_n + i * 16 + col) * 64 + cs * 8];
      }
#pragma unroll
      for (int mi = 0; mi < 4; ++mi)
#pragma unroll
        for (int ni = 0; ni < 4; ++ni)
          acc[mi][ni] = mfma_bf16_32(af[mi], bfr[ni], acc[mi][ni]);
    }
  }

  const int sel = n_blk >> 11;   // block-uniform (ranges are 2048-aligned)
#pragma unroll
  for (int mi = 0; mi < 4; ++mi)
#pragma unroll
    for (int ni = 0; ni < 4; ++ni)
#pragma unroll
      for (int r = 0; r < 4; ++r) {
        int m = m_blk + w_m + mi * 16 + quad * 4 + r;
        int n = n_blk + w_n + ni * 16 + col;
        float v = acc[mi][ni][r];
        if (MODE == 0) {
          int n_l = n & (H_ - 1);
          int head = n_l >> 7, hd = n_l & (HD_ - 1);
          int b = m >> 11, s = m & (S_ - 1);
          if (sel == 2) {
            outV[(((size_t)(b * NH_ + head)) * HD_ + hd) * S_ + s] = (f16_t)v;
          } else {
            size_t idx = (((size_t)(b * NH_ + head)) * S_ + s) * HD_ + hd;
            if (sel == 0) outQ[idx] = (bf16_t)v;
            else          outK[idx] = (bf16_t)v;
          }
        } else {
          outF[(size_t)m * H_ + n] = v;
        }
      }
}

// ---------------- RoPE (in-place on [B,NH,S,HD] bf16) ----------------
__global__ void rope_kernel(bf16_t* __restrict__ X) {
  int i = blockIdx.x * blockDim.x + threadIdx.x;  // B*NH*S*64 threads
  int d  = i & 63;
  int s  = (i >> 6) & (S_ - 1);
  int bh = i >> 17;
  if (bh >= B_ * NH_) return;
  float ang = (float)s * powf(10000.0f, -(float)d * (1.0f / 64.0f));
  float c = cosf(ang), sn = sinf(ang);
  size_t base = ((size_t)bh * S_ + s) * HD_ + d;
  float x1 = (float)X[base], x2 = (float)X[base + 64];
  X[base]      = (bf16_t)(x1 * c - x2 * sn);
  X[base + 64] = (bf16_t)(x2 * c + x1 * sn);
}

// ---------------- Flash causal attention (S^T form, swizzled LDS) ----------------
// St = K.Q^T : C-layout col = q (lane&15), row = k (quad*4+r)
//   -> softmax over k: in-register (16 vals) + shfl_xor(16),(32)
//   -> post-exp P^T fragment IS the B-operand of mfma_f32_16x16x16f16 (no LDS trip)
// O^T = V^T.P^T in C-layout (col=q, row=d)
// Q,K: [B,NH,S,HD] bf16; Vt: [B,NH,HD,S] fp16; Out: [B,S,H] bf16
__global__ __launch_bounds__(256, 4)
void flash_attn(const bf16_t* __restrict__ Q, const bf16_t* __restrict__ K,
                const f16_t* __restrict__ Vt, bf16_t* __restrict__ Out) {
  __shared__ bf16_t sK[64 * 128];  // 16 KB; row = 16 chunks of 16B, XOR-swizzled
  __shared__ f16_t  sV[128 * 64];  // 16 KB [d][s_tile]; row = 8 chunks, XOR-swizzled

  const int tid  = threadIdx.x;
  const int lane = tid & 63;
  const int w    = tid >> 6;
  const int col  = lane & 15;
  const int quad = lane >> 4;

  const int qt = gridDim.x - 1 - blockIdx.x;  // long blocks first (tail balance)
  const int bh = blockIdx.y;
  const int b  = bh >> 4;
  const int h  = bh & (NH_ - 1);

  const bf16_t* Qb = Q  + (size_t)bh * S_ * HD_;
  const bf16_t* Kb = K  + (size_t)bh * S_ * HD_;
  const f16_t*  Vb = Vt + (size_t)bh * HD_ * S_;

  // Q fragments in registers (wave owns 16 q-rows), pre-scaled by 1/sqrt(HD)
  const float scale = 0.08838834764831845f;
  const bf16_t* Qrow = Qb + (size_t)(qt * 64 + w * 16 + col) * HD_;
  bf16x8 qf[4];
#pragma unroll
  for (int kc = 0; kc < 4; ++kc) {
    qf[kc] = *(const bf16x8*)(Qrow + kc * 32 + quad * 8);
#pragma unroll
    for (int j = 0; j < 8; ++j) qf[kc][j] = (bf16_t)((float)qf[kc][j] * scale);
  }

  f32x4 oacc[8] = {};
  float m_i = -1e30f, l_i = 0.f;

  for (int kt = 0; kt <= qt; ++kt) {
    __syncthreads();
    // stage K tile (64x128 bf16) and V tile (128x64 f16), XOR-swizzled source chunks
#pragma unroll
    for (int p = 0; p < 4; ++p) {
      int seg = w * 4 + p;
      int krow = seg * 4 + (lane >> 4);                 // 4 rows/seg (256B rows)
      int kchunk = (lane & 15) ^ (krow & 7);
      gl_lds16(Kb + (size_t)(kt * 64 + krow) * HD_ + kchunk * 8, &sK[seg * 512]);
      int vrow = seg * 8 + (lane >> 3);                 // 8 rows/seg (128B rows)
      int vchunk = (lane & 7) ^ (vrow & 7);
      gl_lds16(Vb + (size_t)vrow * S_ + kt * 64 + vchunk * 8, &sV[seg * 512]);
    }
    __syncthreads();

    // St = K.Q^T  (4 k-tiles of 16); K rows have row&7 == col&7
    f32x4 st[4] = {};
#pragma unroll
    for (int kc = 0; kc < 4; ++kc) {
#pragma unroll
      for (int t = 0; t < 4; ++t) {
        int cs = (kc * 4 + quad) ^ (col & 7);
        bf16x8 kf = *(const bf16x8*)&sK[(t * 16 + col) * 128 + cs * 8];
        st[t] = mfma_bf16_32(kf, qf[kc], st[t]);
      }
    }

    // causal mask (diagonal tile only = last iteration)
    if (kt == qt) {
      int ql = w * 16 + col;
#pragma unroll
      for (int t = 0; t < 4; ++t)
#pragma unroll
        for (int r = 0; r < 4; ++r)
          if (t * 16 + quad * 4 + r > ql) st[t][r] = -1e30f;
    }

    // online softmax: per-lane q; k spread over 16 regs + quads
    float mx = st[0][0];
#pragma unroll
    for (int t = 0; t < 4; ++t)
#pragma unroll
      for (int r = 0; r < 4; ++r) mx = fmaxf(mx, st[t][r]);
    mx = fmaxf(mx, __shfl_xor(mx, 16, 64));
    mx = fmaxf(mx, __shfl_xor(mx, 32, 64));
    float mn = fmaxf(m_i, mx);
    float alpha = __expf(m_i - mn);
    m_i = mn;

    float sum = 0.f;
    f16x4 pf[4];
#pragma unroll
    for (int t = 0; t < 4; ++t)
#pragma unroll
      for (int r = 0; r < 4; ++r) {
        float p = __expf(st[t][r] - mn);
        sum += p;
        pf[t][r] = (f16_t)p;
      }
    sum += __shfl_xor(sum, 16, 64);
    sum += __shfl_xor(sum, 32, 64);
    l_i = l_i * alpha + sum;

#pragma unroll
    for (int dt = 0; dt < 8; ++dt)
#pragma unroll
      for (int r = 0; r < 4; ++r) oacc[dt][r] *= alpha;

    // O^T += V^T.P^T  — P fragment straight from registers; V rows row&7==col&7
#pragma unroll
    for (int t = 0; t < 4; ++t) {
#pragma unroll
      for (int dt = 0; dt < 8; ++dt) {
        int g = t * 2 + (quad >> 1);
        f16x4 vf = *(const f16x4*)&sV[(dt * 16 + col) * 64 +
                                      ((g ^ (col & 7)) * 8) + (quad & 1) * 4];
        oacc[dt] = mfma_f16_16(vf, pf[t], oacc[dt]);
      }
    }
  }

  float inv = 1.0f / l_i;
  int qg = qt * 64 + w * 16 + col;
  bf16_t* Orow = Out + ((size_t)b * S_ + qg) * H_ + h * HD_;
#pragma unroll
  for (int dt = 0; dt < 8; ++dt) {
    bf16x4 o4;
#pragma unroll
    for (int r = 0; r < 4; ++r) o4[r] = (bf16_t)(oacc[dt][r] * inv);
    *(bf16x4*)(Orow + dt * 16 + quad * 4) = o4;
  }
}

// ---------------- launch ----------------
extern "C" void kernel_launch(void* const* d_in, const int* in_sizes, int n_in,
                              void* d_out, int out_size, void* d_ws, size_t ws_size,
                              hipStream_t stream) {
  const float* hs = (const float*)d_in[0];
  // d_in[1] = attention_mask: exactly causal tril(0,-1e9) -> applied analytically
  const float* Wq = (const float*)d_in[2];
  const float* Wk = (const float*)d_in[3];
  const float* Wv = (const float*)d_in[4];
  const float* Wo = (const float*)d_in[5];
  float* out = (float*)d_out;

  char* ws = (char*)d_ws;
  size_t off = 0;
  auto alloc = [&](size_t bytes) -> void* {
    void* p = ws + off;
    off += (bytes + 255) & ~(size_t)255;
    return p;
  };
  bf16_t* hs_b  = (bf16_t*)alloc((size_t)M_ * H_ * 2);
  bf16_t* wqkv  = (bf16_t*)alloc((size_t)3 * H_ * H_ * 2);  // Wq|Wk|Wv contiguous
  bf16_t* wo_b  = (bf16_t*)alloc((size_t)H_ * H_ * 2);
  bf16_t* Qbuf  = (bf16_t*)alloc((size_t)M_ * H_ * 2);
  bf16_t* Kbuf  = (bf16_t*)alloc((size_t)M_ * H_ * 2);
  f16_t*  Vtbuf = (f16_t*)alloc((size_t)M_ * H_ * 2);
  bf16_t* attn  = (bf16_t*)alloc((size_t)M_ * H_ * 2);

  cvt_f32_bf16<<<4096, 256, 0, stream>>>(hs, hs_b, M_ * H_);
  cvt_f32_bf16<<<2048, 256, 0, stream>>>(Wq, wqkv,               H_ * H_);
  cvt_f32_bf16<<<2048, 256, 0, stream>>>(Wk, wqkv + H_ * H_,     H_ * H_);
  cvt_f32_bf16<<<2048, 256, 0, stream>>>(Wv, wqkv + 2 * H_ * H_, H_ * H_);
  cvt_f32_bf16<<<2048, 256, 0, stream>>>(Wo, wo_b, H_ * H_);

  // fused QKV projection: [4096 x 6144] = hs_b . wqkv^T
  gemm_mfma<0><<<dim3(48, 32), 256, 0, stream>>>(hs_b, wqkv, Qbuf, Kbuf, Vtbuf,
                                                 nullptr, H_);

  int rope_threads = B_ * NH_ * S_ * 64;
  rope_kernel<<<rope_threads / 256, 256, 0, stream>>>(Qbuf);
  rope_kernel<<<rope_threads / 256, 256, 0, stream>>>(Kbuf);

  flash_attn<<<dim3(32, 32), 256, 0, stream>>>(Qbuf, Kbuf, Vtbuf, attn);

  // output projection (fp32 out)
  gemm_mfma<1><<<dim3(16, 32), 256, 0, stream>>>(attn, wo_b, nullptr, nullptr,
                                                 nullptr, out, H_);
}